// Round 13
// baseline (222.390 us; speedup 1.0000x reference)
//
#include <hip/hip_runtime.h>
#include <hip/hip_bf16.h>

#define NN 50000
#define NE 1200000
#define H 64
#define NBUCK 196          // coarse buckets of 256 nodes (dst>>8)
#define CHUNK 4096
#define NCHUNK ((NE + CHUNK - 1) / CHUNK)   // 293
#define K1B 782            // kA encoder blocks (ceil(3125 groups / 4 waves))
#define HISTB 256          // histogram blocks appended to kA grid
#define MAXB 7000          // per-bucket record capacity in k2d LDS (mean 6122, +11 sigma)

using bf16x8 = __attribute__((ext_vector_type(8))) short;
using f32x4  = __attribute__((ext_vector_type(4))) float;

static __device__ __forceinline__ unsigned short f2bf(float f) {
    __hip_bfloat16 h = __float2bfloat16(f);
    return *reinterpret_cast<unsigned short*>(&h);
}
static __device__ __forceinline__ float bf2f(unsigned short u) {
    return __uint_as_float((unsigned)u << 16);
}

// ---------------------------------------------------------------------------
// kA: fused  [blocks 0..K1B-1]  node encoder + 4 projections (MFMA)
//            [blocks K1B..K1B+HISTB-1]  coarse-bucket histogram of dst
//            (device-scope atomicAdd into gbcnt — cross-XCD safe)
// ---------------------------------------------------------------------------
__global__ __launch_bounds__(256) void kA_node_hist(
    const float* __restrict__ x,
    const float* __restrict__ Wn1, const float* __restrict__ bn1,
    const float* __restrict__ Wn2, const float* __restrict__ bn2,
    const float* __restrict__ Wm1, const float* __restrict__ Wu1,
    const int* __restrict__ eidx,
    unsigned short* __restrict__ Ab, unsigned short* __restrict__ Bb,
    unsigned short* __restrict__ HUb, int* __restrict__ gbcnt)
{
    __shared__ unsigned short hbuf[4][16 * 64];   // 8 KB (hist part reuses as int[NBUCK])
    __shared__ bf16x8 wfrag[4][4][2][64];         // 32 KB

    const int tid = threadIdx.x;

    if (blockIdx.x >= K1B) {
        // ---- histogram part ----
        int* hl = (int*)&hbuf[0][0];
        for (int i = tid; i < NBUCK; i += 256) hl[i] = 0;
        __syncthreads();
        const int hb = blockIdx.x - K1B;
        const int stride = HISTB * 256;
        for (int e = hb * 256 + tid; e < NE; e += stride)
            atomicAdd(&hl[eidx[NE + e] >> 8], 1);
        __syncthreads();
        for (int i = tid; i < NBUCK; i += 256)
            if (hl[i]) atomicAdd(&gbcnt[i], hl[i]);
        return;
    }

    // ---- node encoder part ----
    const int w   = tid >> 6;
    const int l   = tid & 63;
    const int l15 = l & 15;
    const int lb  = l >> 4;

    const float* Wmats[4] = { Wn2, Wm1, Wm1 + H * H, Wu1 };
    const float* Wsrc = Wmats[w];
#pragma unroll
    for (int t = 0; t < 4; ++t)
#pragma unroll
        for (int kh = 0; kh < 2; ++kh) {
            bf16x8 f;
#pragma unroll
            for (int j = 0; j < 8; ++j) {
                const int k = kh * 32 + lb * 8 + j;
                f[j] = (short)f2bf(Wsrc[k * H + 16 * t + l15]);
            }
            wfrag[w][t][kh][l] = f;
        }

    bf16x8 b1frag[4];
    float bn1t[4], bn2t[4];
#pragma unroll
    for (int t = 0; t < 4; ++t) {
        bn1t[t] = bn1[16 * t + l15];
        bn2t[t] = bn2[16 * t + l15];
#pragma unroll
        for (int j = 0; j < 8; ++j) {
            float v = (lb == 0 && j < 5) ? Wn1[j * H + 16 * t + l15] : 0.f;
            b1frag[t][j] = (short)f2bf(v);
        }
    }
    __syncthreads();

    const int g = blockIdx.x * 4 + w;
    if (g * 16 >= NN) return;
    const int n0 = g * 16;
    const f32x4 z4 = {0.f, 0.f, 0.f, 0.f};

    bf16x8 xf = {0, 0, 0, 0, 0, 0, 0, 0};
    if (lb == 0) {
        const float* xr = x + (size_t)(n0 + l15) * 5;
#pragma unroll
        for (int j = 0; j < 5; ++j) xf[j] = (short)f2bf(xr[j]);
    }
    f32x4 acc1[4];
#pragma unroll
    for (int t = 0; t < 4; ++t)
        acc1[t] = __builtin_amdgcn_mfma_f32_16x16x32_bf16(xf, b1frag[t], z4, 0, 0, 0);
#pragma unroll
    for (int t = 0; t < 4; ++t)
#pragma unroll
        for (int q = 0; q < 4; ++q) {
            const int m = lb * 4 + q;
            const int idx = (m * 64 + 16 * t + l15) ^ ((m & 7) << 3);
            hbuf[w][idx] = f2bf(fmaxf(acc1[t][q] + bn1t[t], 0.f));
        }
    __builtin_amdgcn_wave_barrier();

    auto rdA = [&](int kh) {
        const int idx = (l15 * 64 + kh * 32 + lb * 8) ^ ((l15 & 7) << 3);
        return *reinterpret_cast<const bf16x8*>(&hbuf[w][idx]);
    };

    {
        bf16x8 a0 = rdA(0), a1 = rdA(1);
        __builtin_amdgcn_wave_barrier();
        f32x4 acc[4];
#pragma unroll
        for (int t = 0; t < 4; ++t) {
            acc[t] = __builtin_amdgcn_mfma_f32_16x16x32_bf16(a0, wfrag[0][t][0][l], z4, 0, 0, 0);
            acc[t] = __builtin_amdgcn_mfma_f32_16x16x32_bf16(a1, wfrag[0][t][1][l], acc[t], 0, 0, 0);
        }
#pragma unroll
        for (int t = 0; t < 4; ++t)
#pragma unroll
            for (int q = 0; q < 4; ++q) {
                const int m = lb * 4 + q;
                const int idx = (m * 64 + 16 * t + l15) ^ ((m & 7) << 3);
                hbuf[w][idx] = f2bf(acc[t][q] + bn2t[t]);
            }
        __builtin_amdgcn_wave_barrier();
    }

    bf16x8 h0 = rdA(0), h1v = rdA(1);
#pragma unroll
    for (int t = 0; t < 4; ++t) {
        f32x4 acc = __builtin_amdgcn_mfma_f32_16x16x32_bf16(h0, wfrag[1][t][0][l], z4, 0, 0, 0);
        acc = __builtin_amdgcn_mfma_f32_16x16x32_bf16(h1v, wfrag[1][t][1][l], acc, 0, 0, 0);
#pragma unroll
        for (int q = 0; q < 4; ++q)
            Ab[(size_t)(n0 + lb * 4 + q) * H + 16 * t + l15] = f2bf(acc[q]);
    }
#pragma unroll
    for (int t = 0; t < 4; ++t) {
        f32x4 acc = __builtin_amdgcn_mfma_f32_16x16x32_bf16(h0, wfrag[2][t][0][l], z4, 0, 0, 0);
        acc = __builtin_amdgcn_mfma_f32_16x16x32_bf16(h1v, wfrag[2][t][1][l], acc, 0, 0, 0);
#pragma unroll
        for (int q = 0; q < 4; ++q)
            Bb[(size_t)(n0 + lb * 4 + q) * H + 16 * t + l15] = f2bf(acc[q]);
    }
#pragma unroll
    for (int t = 0; t < 4; ++t) {
        f32x4 acc = __builtin_amdgcn_mfma_f32_16x16x32_bf16(h0, wfrag[3][t][0][l], z4, 0, 0, 0);
        acc = __builtin_amdgcn_mfma_f32_16x16x32_bf16(h1v, wfrag[3][t][1][l], acc, 0, 0, 0);
#pragma unroll
        for (int q = 0; q < 4; ++q)
            HUb[(size_t)(n0 + lb * 4 + q) * H + 16 * t + l15] = f2bf(acc[q]);
    }
}

// ---------------------------------------------------------------------------
// kB: fused  single-block scan of bucket counts -> bbase/gcur  +  k0 weight
//     folding (We2, bp, Wma, bma). Independent phases, one launch.
// ---------------------------------------------------------------------------
__global__ __launch_bounds__(256) void kB_scan_prep(
    const int* __restrict__ gbcnt, int* __restrict__ bbase, int* __restrict__ gcur,
    const float* __restrict__ We, const float* __restrict__ be,
    const float* __restrict__ Wm1, const float* __restrict__ bm1,
    const float* __restrict__ Wm2, const float* __restrict__ bm2,
    const float* __restrict__ Wu1,
    float* __restrict__ We2, float* __restrict__ bp,
    float* __restrict__ Wma, float* __restrict__ bma)
{
    __shared__ int wsum[4];
    const int tid = threadIdx.x, lane = tid & 63, wv = tid >> 6;

    // ---- scan part ----
    const int v = (tid < NBUCK) ? gbcnt[tid] : 0;
    int s = v;
#pragma unroll
    for (int d = 1; d < 64; d <<= 1) {
        int t = __shfl_up(s, (unsigned)d, 64);
        if (lane >= d) s += t;
    }
    if (lane == 63) wsum[wv] = s;
    __syncthreads();
    int wb = 0;
#pragma unroll
    for (int k = 0; k < 4; ++k) wb += (k < wv) ? wsum[k] : 0;
    const int excl = wb + s - v;
    if (tid < NBUCK) {
        bbase[tid] = excl;
        gcur[tid]  = excl;
        if (tid == NBUCK - 1) bbase[NBUCK] = excl + v;
    }

    // ---- prep part (k0) ----
    const int j = tid & (H - 1);
    const int q = tid >> 6;
    if (q == 0) {
        float s0 = 0.f, s1 = 0.f, sb = 0.f;
        for (int k = 0; k < H; ++k) {
            const float w = Wm1[(2 * H + k) * H + j];
            s0 = fmaf(We[k], w, s0);
            s1 = fmaf(We[H + k], w, s1);
            sb = fmaf(be[k], w, sb);
        }
        We2[j]     = s0;
        We2[H + j] = s1;
        bp[j]      = sb + bm1[j];
        float sm = 0.f;
        for (int l = 0; l < H; ++l)
            sm = fmaf(bm2[l], Wu1[(H + l) * H + j], sm);
        bma[j] = sm;
    }
    for (int k = q * (H / 4); k < (q + 1) * (H / 4); ++k) {
        float s2 = 0.f;
        for (int l = 0; l < H; ++l)
            s2 = fmaf(Wm2[k * H + l], Wu1[(H + l) * H + j], s2);
        Wma[k * H + j] = s2;
    }
}

// ---------------------------------------------------------------------------
// k2s: chunk counting-sort into bucket-sorted rec (sequential flush runs)
// ---------------------------------------------------------------------------
__global__ __launch_bounds__(256) void k2s_sort(
    const int* __restrict__ eidx, const float* __restrict__ ea,
    int* __restrict__ gcur, uint2* __restrict__ rec)
{
    __shared__ int hcnt[256], delta[256], c2[256];
    __shared__ int wsum[4];
    __shared__ uint2 srt[CHUNK];
    const int tid = threadIdx.x, lane = tid & 63, wv = tid >> 6;
    const int cbase = blockIdx.x * CHUNK;
    const int nck = (NE - cbase < CHUNK) ? (NE - cbase) : CHUNK;

    hcnt[tid] = 0;
    __syncthreads();

    unsigned rx[16], ry[16];
#pragma unroll
    for (int k = 0; k < 16; ++k) {
        const int i = k * 256 + tid;
        if (i < nck) {
            const int e = cbase + i;
            const int dst = eidx[NE + e];
            const int src = eidx[e];
            const float2 q = ((const float2*)ea)[e];
            rx[k] = (unsigned)src | ((unsigned)(dst & 255) << 16)
                  | ((unsigned)(dst >> 8) << 24);
            ry[k] = (unsigned)f2bf(q.x) | ((unsigned)f2bf(q.y) << 16);
            atomicAdd(&hcnt[dst >> 8], 1);
        } else rx[k] = 0xFFFFFFFFu;
    }
    __syncthreads();

    const int v = hcnt[tid];
    int s = v;
#pragma unroll
    for (int d = 1; d < 64; d <<= 1) {
        int t = __shfl_up(s, (unsigned)d, 64);
        if (lane >= d) s += t;
    }
    if (lane == 63) wsum[wv] = s;
    __syncthreads();
    int wb = 0;
#pragma unroll
    for (int k = 0; k < 4; ++k) wb += (k < wv) ? wsum[k] : 0;
    const int excl = wb + s - v;
    c2[tid] = excl;
    if (tid < NBUCK) {
        const int base = v ? atomicAdd(&gcur[tid], v) : 0;
        delta[tid] = base - excl;
    }
    __syncthreads();

#pragma unroll
    for (int k = 0; k < 16; ++k) {
        if (rx[k] != 0xFFFFFFFFu) {
            const int b = rx[k] >> 24;
            const int slot = atomicAdd(&c2[b], 1);
            srt[slot] = (uint2){rx[k], ry[k]};
        }
    }
    __syncthreads();

    for (int i = tid; i < nck; i += 256) {
        const uint2 rr = srt[i];
        rec[i + delta[rr.x >> 24]] = rr;
    }
}

// ---------------------------------------------------------------------------
// k2d: per-coarse-bucket exact CSR with LDS-staged output: hist pass (read),
// LDS scan -> off[], scatter pass into LDS srt, LINEAR coalesced flush.
// rec2: { src , bf16 ea pair }
// ---------------------------------------------------------------------------
__global__ __launch_bounds__(256) void k2d_csr(
    const int* __restrict__ bbase, const uint2* __restrict__ rec,
    int* __restrict__ off, uint2* __restrict__ rec2)
{
    __shared__ int hl[256];
    __shared__ int cur[256];
    __shared__ int wsum[4];
    __shared__ uint2 srt[MAXB];     // 56 KB
    const int tid = threadIdx.x, lane = tid & 63, wv = tid >> 6;
    const int b = blockIdx.x;
    const int r0 = bbase[b], r1 = bbase[b + 1];
    const int nr = r1 - r0;

    hl[tid] = 0;
    __syncthreads();
    for (int i = tid; i < nr; i += 256)
        atomicAdd(&hl[(rec[r0 + i].x >> 16) & 255], 1);
    __syncthreads();

    const int v = hl[tid];
    int s = v;
#pragma unroll
    for (int d = 1; d < 64; d <<= 1) {
        int t = __shfl_up(s, (unsigned)d, 64);
        if (lane >= d) s += t;
    }
    if (lane == 63) wsum[wv] = s;
    __syncthreads();
    int wb = 0;
#pragma unroll
    for (int k = 0; k < 4; ++k) wb += (k < wv) ? wsum[k] : 0;
    const int excl = wb + s - v;
    cur[tid] = excl;                        // bucket-local base
    const int n = b * 256 + tid;
    if (n < NN) off[n] = r0 + excl;
    if (b == NBUCK - 1 && tid == 0) off[NN] = NE;
    __syncthreads();

    if (nr <= MAXB) {
        for (int i = tid; i < nr; i += 256) {
            const uint2 rr = rec[r0 + i];          // L2-hot second read
            const int ln = (rr.x >> 16) & 255;
            const int slot = atomicAdd(&cur[ln], 1);
            srt[slot] = (uint2){rr.x & 0xFFFFu, rr.y};
        }
        __syncthreads();
        for (int i = tid; i < nr; i += 256)        // linear coalesced flush
            rec2[r0 + i] = srt[i];
    } else {
        // overflow fallback (never expected on this graph): direct scatter
        for (int i = tid; i < nr; i += 256) {
            const uint2 rr = rec[r0 + i];
            const int ln = (rr.x >> 16) & 255;
            const int slot = atomicAdd(&cur[ln], 1);
            rec2[r0 + slot] = (uint2){rr.x & 0xFFFFu, rr.y};
        }
    }
}

// ---------------------------------------------------------------------------
// k3r: PURE aggregation. One wave per node, zero LDS, max occupancy.
//   Rb[n] = bf16( sum_e relu(Ab[n] + Bb[src] + ea*We2 + bp) )
// ---------------------------------------------------------------------------
__global__ __launch_bounds__(256, 8) void k3r_agg(
    const int* __restrict__ off, const uint2* __restrict__ rec2,
    const unsigned short* __restrict__ Ab, const unsigned short* __restrict__ Bb,
    const float* __restrict__ We2, const float* __restrict__ bp,
    unsigned short* __restrict__ Rb)
{
    const int j = threadIdx.x & 63;
    const int wid = (blockIdx.x * 256 + threadIdx.x) >> 6;
    const int nw = (gridDim.x * 256) >> 6;
    const float w0 = We2[j], w1 = We2[H + j], bpj = bp[j];

    for (int n = wid; n < NN; n += nw) {
        const int e0 = __builtin_amdgcn_readfirstlane(off[n]);
        const int e1 = __builtin_amdgcn_readfirstlane(off[n + 1]);
        const float a = bf2f(Ab[(size_t)n * H + j]) + bpj;
        float rsum = 0.f;

        auto proc = [&](unsigned rx, unsigned ry) {
            const float bb = bf2f(Bb[(size_t)(rx & 0xFFFFu) * H + j]);
            float z = a + bb;
            z = fmaf(__uint_as_float(ry << 16), w0, z);
            z = fmaf(__uint_as_float(ry & 0xFFFF0000u), w1, z);
            rsum += fmaxf(z, 0.f);
        };

        int e = e0;
        if ((e & 1) && e < e1) {
            const uint2 r = rec2[e];
            proc(r.x, r.y);
            ++e;
        }
        for (; e + 8 <= e1; e += 8) {
            const uint4 p0 = *(const uint4*)(rec2 + e);
            const uint4 p1 = *(const uint4*)(rec2 + e + 2);
            const uint4 p2 = *(const uint4*)(rec2 + e + 4);
            const uint4 p3 = *(const uint4*)(rec2 + e + 6);
            proc(p0.x, p0.y); proc(p0.z, p0.w);
            proc(p1.x, p1.y); proc(p1.z, p1.w);
            proc(p2.x, p2.y); proc(p2.z, p2.w);
            proc(p3.x, p3.y); proc(p3.z, p3.w);
        }
        for (; e + 2 <= e1; e += 2) {
            const uint4 p0 = *(const uint4*)(rec2 + e);
            proc(p0.x, p0.y); proc(p0.z, p0.w);
        }
        if (e < e1) {
            const uint2 r = rec2[e];
            proc(r.x, r.y);
        }
        Rb[(size_t)n * H + j] = f2bf(rsum);
    }
}

// ---------------------------------------------------------------------------
// k4_mfma: update MLP on matrix cores, 16-node tiles.
// ---------------------------------------------------------------------------
__global__ __launch_bounds__(256) void k4_mfma(
    const int* __restrict__ off,
    const unsigned short* __restrict__ Rb, const unsigned short* __restrict__ HUb,
    const float* __restrict__ Wma, const float* __restrict__ bma,
    const float* __restrict__ bu1,
    const float* __restrict__ Wu2, const float* __restrict__ bu2,
    float* __restrict__ out)
{
    __shared__ unsigned short hbuf[4][16 * 64];   // 8 KB
    __shared__ bf16x8 wfrag[2][4][2][64];         // 16 KB

    const int tid = threadIdx.x;
    const int w   = tid >> 6;
    const int l   = tid & 63;
    const int l15 = l & 15;
    const int lb  = l >> 4;

    if (w < 2) {
        const float* Wsrc = (w == 0) ? Wma : Wu2;
#pragma unroll
        for (int t = 0; t < 4; ++t)
#pragma unroll
            for (int kh = 0; kh < 2; ++kh) {
                bf16x8 f;
#pragma unroll
                for (int j = 0; j < 8; ++j) {
                    const int k = kh * 32 + lb * 8 + j;
                    f[j] = (short)f2bf(Wsrc[k * H + 16 * t + l15]);
                }
                wfrag[w][t][kh][l] = f;
            }
    }
    __syncthreads();

    const int g = blockIdx.x * 4 + w;
    if (g * 16 >= NN) return;
    const int n0 = g * 16;
    const f32x4 z4 = {0.f, 0.f, 0.f, 0.f};

    const bf16x8 r0 = *(const bf16x8*)(Rb + (size_t)(n0 + l15) * H + lb * 8);
    const bf16x8 r1 = *(const bf16x8*)(Rb + (size_t)(n0 + l15) * H + 32 + lb * 8);

    const float cntv = (float)(off[n0 + l15 + 1] - off[n0 + l15]);

    float bmat[4], bu1t[4], bu2t[4];
#pragma unroll
    for (int t = 0; t < 4; ++t) {
        bmat[t] = bma[16 * t + l15];
        bu1t[t] = bu1[16 * t + l15];
        bu2t[t] = bu2[16 * t + l15];
    }

#pragma unroll
    for (int t = 0; t < 4; ++t) {
        f32x4 acc = __builtin_amdgcn_mfma_f32_16x16x32_bf16(r0, wfrag[0][t][0][l], z4, 0, 0, 0);
        acc = __builtin_amdgcn_mfma_f32_16x16x32_bf16(r1, wfrag[0][t][1][l], acc, 0, 0, 0);
#pragma unroll
        for (int q = 0; q < 4; ++q) {
            const int row = lb * 4 + q;
            const float c  = __shfl(cntv, row, 64);
            const float cc = fmaxf(c, 1.0f);
            const float hu = bf2f(HUb[(size_t)(n0 + row) * H + 16 * t + l15]);
            float z = hu + fmaf(c, bmat[t], acc[q]) / cc + bu1t[t];
            z = fmaxf(z, 0.f);
            const int idx = (row * 64 + 16 * t + l15) ^ ((row & 7) << 3);
            hbuf[w][idx] = f2bf(z);
        }
    }
    __builtin_amdgcn_wave_barrier();

    const int ia0 = (l15 * 64 + 0  + lb * 8) ^ ((l15 & 7) << 3);
    const int ia1 = (l15 * 64 + 32 + lb * 8) ^ ((l15 & 7) << 3);
    const bf16x8 a0 = *reinterpret_cast<const bf16x8*>(&hbuf[w][ia0]);
    const bf16x8 a1 = *reinterpret_cast<const bf16x8*>(&hbuf[w][ia1]);

#pragma unroll
    for (int t = 0; t < 4; ++t) {
        f32x4 acc = __builtin_amdgcn_mfma_f32_16x16x32_bf16(a0, wfrag[1][t][0][l], z4, 0, 0, 0);
        acc = __builtin_amdgcn_mfma_f32_16x16x32_bf16(a1, wfrag[1][t][1][l], acc, 0, 0, 0);
#pragma unroll
        for (int q = 0; q < 4; ++q)
            out[(size_t)(n0 + lb * 4 + q) * H + 16 * t + l15] = acc[q] + bu2t[t];
    }
}

// ---------------------------------------------------------------------------
extern "C" void kernel_launch(void* const* d_in, const int* in_sizes, int n_in,
                              void* d_out, int out_size, void* d_ws, size_t ws_size,
                              hipStream_t stream) {
    (void)in_sizes; (void)n_in; (void)out_size; (void)ws_size;
    const float* x    = (const float*)d_in[0];
    const float* eatt = (const float*)d_in[1];
    const int*   eidx = (const int*)d_in[2];
    const float* Wn1  = (const float*)d_in[3];
    const float* bn1  = (const float*)d_in[4];
    const float* Wn2  = (const float*)d_in[5];
    const float* bn2  = (const float*)d_in[6];
    const float* We   = (const float*)d_in[7];
    const float* be   = (const float*)d_in[8];
    const float* Wm1  = (const float*)d_in[9];
    const float* bm1  = (const float*)d_in[10];
    const float* Wm2  = (const float*)d_in[11];
    const float* bm2  = (const float*)d_in[12];
    const float* Wu1  = (const float*)d_in[13];
    const float* bu1  = (const float*)d_in[14];
    const float* Wu2  = (const float*)d_in[15];
    const float* bu2  = (const float*)d_in[16];
    float* out = (float*)d_out;

    char* wsb = (char*)d_ws;
    unsigned short* Ab  = (unsigned short*)wsb;                    // NN*H bf16
    unsigned short* Bb  = Ab + (size_t)NN * H;                     // NN*H bf16
    unsigned short* HUb = Bb + (size_t)NN * H;                     // NN*H bf16
    unsigned short* Rb  = HUb + (size_t)NN * H;                    // NN*H bf16
    uint2* rec  = (uint2*)(Rb + (size_t)NN * H);                   // NE*8B
    uint2* rec2 = rec + NE;                                        // NE*8B
    int*   off  = (int*)(rec2 + NE);                               // NN+1
    int*   bbase= off + NN + 1;                                    // NBUCK+1
    int*   gbcnt= bbase + NBUCK + 1;                               // NBUCK
    int*   gcur = gbcnt + NBUCK;                                   // NBUCK
    float* We2  = (float*)(gcur + NBUCK);                          // 2*H
    float* bp   = We2 + 2 * H;                                     // H
    float* Wma  = bp + H;                                          // H*H
    float* bma  = Wma + H * H;                                     // H

    hipMemsetAsync(gbcnt, 0, NBUCK * sizeof(int), stream);

    kA_node_hist<<<K1B + HISTB, 256, 0, stream>>>(x, Wn1, bn1, Wn2, bn2,
                                                  Wm1, Wu1, eidx,
                                                  Ab, Bb, HUb, gbcnt);
    kB_scan_prep<<<1, 256, 0, stream>>>(gbcnt, bbase, gcur,
                                        We, be, Wm1, bm1, Wm2, bm2, Wu1,
                                        We2, bp, Wma, bma);
    k2s_sort<<<NCHUNK, 256, 0, stream>>>(eidx, eatt, gcur, rec);
    k2d_csr<<<NBUCK, 256, 0, stream>>>(bbase, rec, off, rec2);
    k3r_agg<<<2048, 256, 0, stream>>>(off, rec2, Ab, Bb, We2, bp, Rb);
    k4_mfma<<<(NN / 16 + 3) / 4, 256, 0, stream>>>(off, Rb, HUb, Wma, bma,
                                                   bu1, Wu2, bu2, out);
}